// Round 6
// baseline (211.449 us; speedup 1.0000x reference)
//
#include <hip/hip_runtime.h>
#include <hip/hip_bf16.h>
#include <stdint.h>

typedef short short8 __attribute__((ext_vector_type(8)));
typedef float f32x4  __attribute__((ext_vector_type(4)));

static constexpr int O_TOT = 28672;
static constexpr int K_TOT = 8192;
static constexpr int M_ROWS = 8;
static constexpr int KW = 1024;            // packed int32 words per output row

// workspace layout
static constexpr size_t WS_X    = 4096;                        // 8 rows x 8192 bf16 = 128KB
static constexpr size_t WS_SG   = WS_X + (size_t)8 * K_TOT * 2;
static constexpr size_t WS_NEED = WS_SG + 64 * 8 * 4 + 64;

// mode: 0 = bf16, 1 = fp16, 2 = f32
__device__ __forceinline__ float dec16(uint16_t u, int mode) {
  if (mode == 0) {
    union { uint32_t i; float f; } v; v.i = ((uint32_t)u) << 16; return v.f;
  } else {
    union { uint16_t u; _Float16 h; } v; v.u = u; return (float)v.h;
  }
}
__device__ __forceinline__ uint16_t f2bf_bits(float f) {
  union { __hip_bfloat16 b; uint16_t u; } v; v.b = __float2bfloat16(f); return v.u;
}

// --- dtype sniffer (vectorized; 1024 samples of row 0) ---
__global__ void sniff_kernel(const uint16_t* __restrict__ x, int* __restrict__ flag) {
  const int t = threadIdx.x;
  int ce = 0, co = 0;
  #pragma unroll
  for (int i = 0; i < 2; ++i) {
    const uint4 u = *reinterpret_cast<const uint4*>(x + (size_t)(t + 64 * i) * 8);
    const uint32_t d[4] = {u.x, u.y, u.z, u.w};
    #pragma unroll
    for (int j = 0; j < 4; ++j) {
      const int elo = (d[j] >> 7)  & 0xFF;   // even-index half
      const int ehi = (d[j] >> 23) & 0xFF;   // odd-index half
      ce += (elo >= 118 && elo <= 131);
      co += (ehi >= 118 && ehi <= 131);
    }
  }
  for (int d = 32; d; d >>= 1) { ce += __shfl_xor(ce, d); co += __shfl_xor(co, d); }
  if (t == 0) {
    int mode;                                  // 512 samples per parity
    if (ce > 358 && co > 358)      mode = 0;   // bf16
    else if (co > 358)             mode = 2;   // f32
    else                           mode = 1;   // fp16
    *flag = mode;
  }
}

// --- prep: decode x rows 0..7 -> bf16 ws, permuted within 8-blocks (0,4,1,5,2,6,3,7) ---
__global__ void prep_kernel(const uint16_t* __restrict__ x16, uint8_t* __restrict__ ws,
                            const int* __restrict__ flag) {
  const int mode = *flag;
  const int tid = blockIdx.x * 256 + threadIdx.x;   // 32 blocks x 256 = 8192
  const int r = tid >> 10, wb = tid & 1023;
  uint16_t s[8];
  if (mode == 2) {
    const float* xF = (const float*)x16;
    #pragma unroll
    for (int j = 0; j < 8; ++j) s[j] = f2bf_bits(xF[(size_t)r * K_TOT + wb * 8 + j]);
  } else {
    const uint4 u = *reinterpret_cast<const uint4*>(x16 + (size_t)r * K_TOT + wb * 8);
    const uint32_t d[4] = {u.x, u.y, u.z, u.w};
    #pragma unroll
    for (int j = 0; j < 8; ++j) {
      const uint16_t raw = (j & 1) ? (uint16_t)(d[j >> 1] >> 16) : (uint16_t)(d[j >> 1] & 0xffffu);
      s[j] = (mode == 0) ? raw : f2bf_bits(dec16(raw, 1));
    }
  }
  uint16_t p[8];
  p[0] = s[0]; p[1] = s[4]; p[2] = s[1]; p[3] = s[5];
  p[4] = s[2]; p[5] = s[6]; p[6] = s[3]; p[7] = s[7];
  uint4 o;
  o.x = (uint32_t)p[0] | ((uint32_t)p[1] << 16);
  o.y = (uint32_t)p[2] | ((uint32_t)p[3] << 16);
  o.z = (uint32_t)p[4] | ((uint32_t)p[5] << 16);
  o.w = (uint32_t)p[6] | ((uint32_t)p[7] << 16);
  *reinterpret_cast<uint4*>((uint16_t*)(ws + WS_X) + (size_t)r * K_TOT + wb * 8) = o;
}

// --- sg: per-(group,row) sums of STAGED bf16 x (must match MFMA operand rounding) ---
__global__ void sg_kernel(uint8_t* __restrict__ ws) {
  const int p = blockIdx.x * 64 + threadIdx.x;      // 8 x 64 = 512
  const int r = p & 7, G = p >> 3;
  const uint16_t* xb = (const uint16_t*)(ws + WS_X) + (size_t)r * K_TOT + G * 128;
  float s = 0.f;
  #pragma unroll
  for (int i = 0; i < 16; ++i) {
    const uint4 u = *reinterpret_cast<const uint4*>(xb + 8 * i);
    const uint32_t d[4] = {u.x, u.y, u.z, u.w};
    #pragma unroll
    for (int j = 0; j < 4; ++j) {
      s += dec16((uint16_t)(d[j] & 0xffffu), 0);
      s += dec16((uint16_t)(d[j] >> 16), 0);
    }
  }
  ((float*)(ws + WS_SG))[G * 8 + r] = s;
}

// --- main: 16 cols/block, 4 waves k-split, LDS reduce ---
__global__ __launch_bounds__(256, 6)
void wq_mfma_kernel(const uint32_t* __restrict__ qweight,
                    const uint32_t* __restrict__ qzeros,
                    const uint16_t* __restrict__ sc16,
                    const uint16_t* __restrict__ b16,
                    void* __restrict__ outv,
                    const uint8_t* __restrict__ ws,
                    const int* __restrict__ flag)
{
  __shared__ float red[4][64][4];                 // 4KB
  const int mode = *flag;
  const float* scF = (const float*)sc16;
  const float* bF  = (const float*)b16;
  const int t = threadIdx.x, wid = t >> 6, lane = t & 63;
  const int c = lane & 15, g4 = lane >> 4;
  const int tile = blockIdx.x;
  const int cg = tile * 16 + c;

  const uint16_t* xb  = (const uint16_t*)(ws + WS_X);
  const float*    sgp = (const float*)(ws + WS_SG);
  const uint32_t* qp  = qweight + (size_t)cg * KW;
  const uint4*  abase = (const uint4*)(xb + (size_t)(c & 7) * K_TOT);
  const int G0   = wid * 16;
  const int boff = 4 * g4;

  // preload this wave's 2 qzeros words for its 16 groups
  const uint2 qz = *reinterpret_cast<const uint2*>(qzeros + cg * 8 + wid * 2);

  f32x4 D = {0.f, 0.f, 0.f, 0.f};
  uint4 qb[3];
  qb[0] = *reinterpret_cast<const uint4*>(qp + 16 * G0 + boff);
  qb[1] = *reinterpret_cast<const uint4*>(qp + 16 * (G0 + 1) + boff);

  #pragma unroll
  for (int T = 0; T < 16; ++T) {                  // fully unrolled: all idx static
    const int G = G0 + T;
    if (T < 14)
      qb[(T + 2) % 3] = *reinterpret_cast<const uint4*>(qp + 16 * (G + 2) + boff);

    const uint4 a0 = abase[16 * G + boff + 0];
    const uint4 a1 = abase[16 * G + boff + 1];
    const uint4 a2 = abase[16 * G + boff + 2];
    const uint4 a3 = abase[16 * G + boff + 3];

    const float sv = (mode == 2) ? scF[cg * 64 + G] : dec16(sc16[cg * 64 + G], mode);
    const f32x4 sgv = *reinterpret_cast<const f32x4*>(sgp + G * 8 + (g4 & 1) * 4);
    const uint32_t zraw = (T < 8) ? qz.x : qz.y;
    const float zf = (float)((zraw >> ((T & 7) * 4)) & 15u);

    const uint4 q = qb[T % 3];
    const uint32_t wv[4] = {q.x, q.y, q.z, q.w};
    const uint4   av[4] = {a0, a1, a2, a3};
    f32x4 tmp = {0.f, 0.f, 0.f, 0.f};
    #pragma unroll
    for (int u = 0; u < 4; ++u) {
      union { uint32_t d[4]; short8 s; } bb;
      bb.d[0] = ( wv[u]        & 0x000F000Fu) | 0x43004300u;
      bb.d[1] = ((wv[u] >> 4)  & 0x000F000Fu) | 0x43004300u;
      bb.d[2] = ((wv[u] >> 8)  & 0x000F000Fu) | 0x43004300u;
      bb.d[3] = ((wv[u] >> 12) & 0x000F000Fu) | 0x43004300u;
      union { uint4 q; short8 s; } aa; aa.q = av[u];
      tmp = __builtin_amdgcn_mfma_f32_16x16x32_bf16(aa.s, bb.s, tmp, 0, 0, 0);
    }
    const float c128z = 128.0f + zf;
    #pragma unroll
    for (int r2 = 0; r2 < 4; ++r2)
      D[r2] += sv * (tmp[r2] - c128z * sgv[r2]);   // rows g4*4+r2 (only g4<2 stored)
  }

  *reinterpret_cast<f32x4*>(&red[wid][lane][0]) = D;
  __syncthreads();

  if (t < 128) {
    const int r = t >> 4, cc = t & 15;
    const int ln = (r >> 2) * 16 + cc, rg = r & 3;
    float v = red[0][ln][rg] + red[1][ln][rg] + red[2][ln][rg] + red[3][ln][rg];
    const int o = tile * 16 + cc;
    v += (mode == 2) ? bF[o] : dec16(b16[o], mode);
    const size_t idx = (size_t)r * O_TOT + o;
    if (mode == 0)      ((__hip_bfloat16*)outv)[idx] = __float2bfloat16(v);
    else if (mode == 1) { union { uint16_t u; _Float16 h; } cv; cv.h = (_Float16)v;
                          ((uint16_t*)outv)[idx] = cv.u; }
    else                ((float*)outv)[idx] = v;
  }
}

// --- verified R4 fallback (used only if ws too small) ---
static constexpr int NTHR = 512, O_PER_IT = 2, ITERS = 14, NBLK = 1024;
__global__ __launch_bounds__(NTHR, 1)
void wq_fallback_kernel(const uint16_t* __restrict__ x16,
                        const uint32_t* __restrict__ qweight,
                        const uint32_t* __restrict__ qzeros,
                        const uint16_t* __restrict__ sc16,
                        const uint16_t* __restrict__ b16,
                        void* __restrict__ outv,
                        const int* __restrict__ flag)
{
  __shared__ float lds[O_PER_IT][M_ROWS][NTHR];
  const int mode = *flag;
  const int t = threadIdx.x;
  const float* xF  = (const float*)x16;
  const float* scF = (const float*)sc16;
  const float* bF  = (const float*)b16;
  float xf[M_ROWS][16];
  {
    const int kbase = 16 * t;
    if (mode == 2) {
      #pragma unroll
      for (int n = 0; n < M_ROWS; ++n)
        #pragma unroll
        for (int i = 0; i < 16; ++i) xf[n][i] = xF[(size_t)n * K_TOT + kbase + i];
    } else {
      #pragma unroll
      for (int n = 0; n < M_ROWS; ++n)
        #pragma unroll
        for (int i = 0; i < 16; ++i) xf[n][i] = dec16(x16[(size_t)n * K_TOT + kbase + i], mode);
    }
  }
  const int g = t >> 3, zsh = (g & 7) * 4, zword = g >> 3;
  for (int it = 0; it < ITERS; ++it) {
    const int obase = blockIdx.x * (ITERS * O_PER_IT) + it * O_PER_IT;
    #pragma unroll
    for (int oi = 0; oi < O_PER_IT; ++oi) {
      const int o = obase + oi;
      const uint32_t zw = qzeros[o * 8 + zword];
      const float z = (float)((zw >> zsh) & 15u);
      const float s = (mode == 2) ? scF[o * 64 + g] : dec16(sc16[o * 64 + g], mode);
      const uint32_t w0 = qweight[(size_t)o * KW + 2 * t];
      const uint32_t w1 = qweight[(size_t)o * KW + 2 * t + 1];
      float d[M_ROWS];
      #pragma unroll
      for (int n = 0; n < M_ROWS; ++n) d[n] = 0.f;
      const uint32_t wv[2] = { w0, w1 };
      #pragma unroll
      for (int w = 0; w < 2; ++w)
        #pragma unroll
        for (int j = 0; j < 8; ++j) {
          const float q = (float)((wv[w] >> (4 * j)) & 15u);
          const float wgt = s * (q - z);
          #pragma unroll
          for (int n = 0; n < M_ROWS; ++n) d[n] = fmaf(wgt, xf[n][8 * w + j], d[n]);
        }
      #pragma unroll
      for (int n = 0; n < M_ROWS; ++n) lds[oi][n][t] = d[n];
    }
    __syncthreads();
    {
      const int wvid = t >> 6, lanei = t & 63;
      #pragma unroll
      for (int cc2 = 0; cc2 < 2; ++cc2) {
        const int p = 2 * wvid + cc2, oi = p >> 3, n = p & 7;
        float v = 0.f;
        #pragma unroll
        for (int i = 0; i < 8; ++i) v += lds[oi][n][lanei + 64 * i];
        v += __shfl_xor(v, 32); v += __shfl_xor(v, 16); v += __shfl_xor(v, 8);
        v += __shfl_xor(v, 4);  v += __shfl_xor(v, 2);  v += __shfl_xor(v, 1);
        if (lanei == 0) {
          const int o = obase + oi;
          const float b = (mode == 2) ? bF[o] : dec16(b16[o], mode);
          const float r = v + b;
          const size_t idx = (size_t)n * O_TOT + o;
          if (mode == 0)      ((__hip_bfloat16*)outv)[idx] = __float2bfloat16(r);
          else if (mode == 1) { union { uint16_t u; _Float16 h; } cc; cc.h = (_Float16)r;
                                ((uint16_t*)outv)[idx] = cc.u; }
          else                ((float*)outv)[idx] = r;
        }
      }
    }
    __syncthreads();
  }
}

extern "C" void kernel_launch(void* const* d_in, const int* in_sizes, int n_in,
                              void* d_out, int out_size, void* d_ws, size_t ws_size,
                              hipStream_t stream)
{
  const uint16_t* x       = (const uint16_t*)d_in[0];
  const uint32_t* qweight = (const uint32_t*)d_in[1];
  const uint32_t* qzeros  = (const uint32_t*)d_in[2];
  const uint16_t* scales  = (const uint16_t*)d_in[3];
  const uint16_t* bias    = (const uint16_t*)d_in[4];
  int* flag = (int*)d_ws;

  hipLaunchKernelGGL(sniff_kernel, dim3(1), dim3(64), 0, stream, x, flag);

  if (ws_size >= WS_NEED) {
    uint8_t* ws = (uint8_t*)d_ws;
    hipLaunchKernelGGL(prep_kernel, dim3(32), dim3(256), 0, stream, x, ws, flag);
    hipLaunchKernelGGL(sg_kernel,   dim3(8),  dim3(64),  0, stream, ws);
    hipLaunchKernelGGL(wq_mfma_kernel, dim3(1792), dim3(256), 0, stream,
                       qweight, qzeros, scales, bias, d_out, ws, flag);
  } else {
    hipLaunchKernelGGL(wq_fallback_kernel, dim3(NBLK), dim3(NTHR), 0, stream,
                       x, qweight, qzeros, scales, bias, d_out, flag);
  }
}

// Round 7
// 94.181 us; speedup vs baseline: 2.2451x; 2.2451x over previous
//
#include <hip/hip_runtime.h>
#include <hip/hip_bf16.h>
#include <stdint.h>

typedef short short8 __attribute__((ext_vector_type(8)));
typedef float f32x4  __attribute__((ext_vector_type(4)));

static constexpr int O_TOT = 28672;
static constexpr int K_TOT = 8192;
static constexpr int M_ROWS = 8;
static constexpr int KW = 1024;            // packed int32 words per output row

// workspace layout
static constexpr size_t WS_X    = 4096;                        // 8 rows x 8192 bf16 = 128KB
static constexpr size_t WS_SG   = WS_X + (size_t)8 * K_TOT * 2;
static constexpr size_t WS_NEED = WS_SG + 64 * 8 * 4 + 64;

// mode: 0 = bf16, 1 = fp16, 2 = f32
__device__ __forceinline__ float dec16(uint16_t u, int mode) {
  if (mode == 0) {
    union { uint32_t i; float f; } v; v.i = ((uint32_t)u) << 16; return v.f;
  } else {
    union { uint16_t u; _Float16 h; } v; v.u = u; return (float)v.h;
  }
}
__device__ __forceinline__ uint16_t f2bf_bits(float f) {
  union { __hip_bfloat16 b; uint16_t u; } v; v.b = __float2bfloat16(f); return v.u;
}

// --- dtype sniffer (verified R5/R6) ---
__global__ void sniff_kernel(const uint16_t* __restrict__ x, int* __restrict__ flag) {
  const int t = threadIdx.x;
  int ce = 0, co = 0;
  #pragma unroll
  for (int i = 0; i < 2; ++i) {
    const uint4 u = *reinterpret_cast<const uint4*>(x + (size_t)(t + 64 * i) * 8);
    const uint32_t d[4] = {u.x, u.y, u.z, u.w};
    #pragma unroll
    for (int j = 0; j < 4; ++j) {
      const int elo = (d[j] >> 7)  & 0xFF;
      const int ehi = (d[j] >> 23) & 0xFF;
      ce += (elo >= 118 && elo <= 131);
      co += (ehi >= 118 && ehi <= 131);
    }
  }
  for (int d = 32; d; d >>= 1) { ce += __shfl_xor(ce, d); co += __shfl_xor(co, d); }
  if (t == 0) {
    int mode;
    if (ce > 358 && co > 358)      mode = 0;   // bf16
    else if (co > 358)             mode = 2;   // f32
    else                           mode = 1;   // fp16
    *flag = mode;
  }
}

// --- prep: decode x rows 0..7 -> bf16 ws (permuted 0,4,1,5,2,6,3,7 per 8-block)
//     + fused per-(group,row) sums of the STAGED bf16 values ---
__global__ __launch_bounds__(256)
void prep_kernel(const uint16_t* __restrict__ x16, uint8_t* __restrict__ ws,
                 const int* __restrict__ flag) {
  __shared__ float psum[256];
  const int mode = *flag;
  const int t = threadIdx.x;
  const int tid = blockIdx.x * 256 + t;             // 32 blocks x 256 = 8192
  const int r = tid >> 10, wb = tid & 1023;
  uint16_t s[8];
  if (mode == 2) {
    const float* xF = (const float*)x16;
    #pragma unroll
    for (int j = 0; j < 8; ++j) s[j] = f2bf_bits(xF[(size_t)r * K_TOT + wb * 8 + j]);
  } else {
    const uint4 u = *reinterpret_cast<const uint4*>(x16 + (size_t)r * K_TOT + wb * 8);
    const uint32_t d[4] = {u.x, u.y, u.z, u.w};
    #pragma unroll
    for (int j = 0; j < 8; ++j) {
      const uint16_t raw = (j & 1) ? (uint16_t)(d[j >> 1] >> 16) : (uint16_t)(d[j >> 1] & 0xffffu);
      s[j] = (mode == 0) ? raw : f2bf_bits(dec16(raw, 1));
    }
  }
  uint16_t p[8];
  p[0] = s[0]; p[1] = s[4]; p[2] = s[1]; p[3] = s[5];
  p[4] = s[2]; p[5] = s[6]; p[6] = s[3]; p[7] = s[7];
  uint4 o;
  o.x = (uint32_t)p[0] | ((uint32_t)p[1] << 16);
  o.y = (uint32_t)p[2] | ((uint32_t)p[3] << 16);
  o.z = (uint32_t)p[4] | ((uint32_t)p[5] << 16);
  o.w = (uint32_t)p[6] | ((uint32_t)p[7] << 16);
  *reinterpret_cast<uint4*>((uint16_t*)(ws + WS_X) + (size_t)r * K_TOT + wb * 8) = o;

  // group-sum of staged (bf16-rounded) values: 16 words per group
  float loc = 0.f;
  #pragma unroll
  for (int j = 0; j < 8; ++j) loc += dec16(p[j], 0);
  psum[t] = loc;
  __syncthreads();
  // threads t = g*16 .. g*16+15 belong to group g (block covers 16 groups of one row)
  #pragma unroll
  for (int st = 8; st; st >>= 1) {
    if ((t & 15) < st) psum[t] += psum[t + st];
    __syncthreads();
  }
  if ((t & 15) == 0) {
    const int g = t >> 4;                           // 0..15 within block
    const int G = (blockIdx.x & 3) * 16 + g;        // absolute group
    ((float*)(ws + WS_SG))[G * 8 + r] = psum[t];
  }
}

// --- main: 16 cols/block, 4 waves k-split (16 groups each), rolled ping-pong loop ---
__global__ __launch_bounds__(256)
void wq_mfma_kernel(const uint32_t* __restrict__ qweight,
                    const uint32_t* __restrict__ qzeros,
                    const uint16_t* __restrict__ sc16,
                    const uint16_t* __restrict__ b16,
                    void* __restrict__ outv,
                    const uint8_t* __restrict__ ws,
                    const int* __restrict__ flag)
{
  __shared__ float red[4][64][4];                 // 4KB
  const int mode = *flag;
  const float* scF = (const float*)sc16;
  const float* bF  = (const float*)b16;
  const int t = threadIdx.x, wid = t >> 6, lane = t & 63;
  const int c = lane & 15, g4 = lane >> 4;
  const int cg = blockIdx.x * 16 + c;

  const uint16_t* xb  = (const uint16_t*)(ws + WS_X);
  const float*    sgp = (const float*)(ws + WS_SG);
  const uint32_t* qp  = qweight + (size_t)cg * KW;
  const uint4*  abase = (const uint4*)(xb + (size_t)(c & 7) * K_TOT);
  const int G0   = wid * 16;
  const int boff = 4 * g4;

  const uint2 qz = *reinterpret_cast<const uint2*>(qzeros + cg * 8 + wid * 2);

  f32x4 D = {0.f, 0.f, 0.f, 0.f};

  // prologue: load step 0 (R5-proven depth-1 ping-pong; rolled loop, no spill)
  uint4 q0 = *reinterpret_cast<const uint4*>(qp + 16 * G0 + boff);
  uint4 a0[4], a1[4]; uint4 q1;
  #pragma unroll
  for (int u = 0; u < 4; ++u) a0[u] = abase[16 * G0 + boff + u];

#define GBODY(TT, QC, AC, QN, AN)                                              \
  do {                                                                         \
    const int Gc = G0 + (TT);                                                  \
    const int Gn = (Gc + 1 <= 63) ? Gc + 1 : 63;                               \
    QN = *reinterpret_cast<const uint4*>(qp + 16 * Gn + boff);                 \
    AN[0] = abase[16 * Gn + boff + 0];                                         \
    AN[1] = abase[16 * Gn + boff + 1];                                         \
    AN[2] = abase[16 * Gn + boff + 2];                                         \
    AN[3] = abase[16 * Gn + boff + 3];                                         \
    f32x4 tmp = {0.f, 0.f, 0.f, 0.f};                                          \
    const uint32_t wv[4] = {QC.x, QC.y, QC.z, QC.w};                           \
    _Pragma("unroll")                                                          \
    for (int u = 0; u < 4; ++u) {                                              \
      union { uint32_t d[4]; short8 s; } bb;                                   \
      bb.d[0] = ( wv[u]        & 0x000F000Fu) | 0x43004300u;                   \
      bb.d[1] = ((wv[u] >> 4)  & 0x000F000Fu) | 0x43004300u;                   \
      bb.d[2] = ((wv[u] >> 8)  & 0x000F000Fu) | 0x43004300u;                   \
      bb.d[3] = ((wv[u] >> 12) & 0x000F000Fu) | 0x43004300u;                   \
      union { uint4 q; short8 s; } aa; aa.q = AC[u];                           \
      tmp = __builtin_amdgcn_mfma_f32_16x16x32_bf16(aa.s, bb.s, tmp, 0, 0, 0); \
    }                                                                          \
    const uint32_t zraw = ((TT) < 8) ? qz.x : qz.y;                            \
    const float zf = (float)((zraw >> (((TT) & 7) * 4)) & 15u);                \
    const float sv = (mode == 2) ? scF[cg * 64 + Gc]                           \
                                 : dec16(sc16[cg * 64 + Gc], mode);            \
    const f32x4 sgv = *reinterpret_cast<const f32x4*>(sgp + Gc * 8 + (g4 & 1) * 4); \
    const float c128z = 128.0f + zf;                                           \
    D[0] += sv * (tmp[0] - c128z * sgv[0]);                                    \
    D[1] += sv * (tmp[1] - c128z * sgv[1]);                                    \
    D[2] += sv * (tmp[2] - c128z * sgv[2]);                                    \
    D[3] += sv * (tmp[3] - c128z * sgv[3]);                                    \
  } while (0)

  for (int T = 0; T < 16; T += 2) {
    GBODY(T,     q0, a0, q1, a1);
    GBODY(T + 1, q1, a1, q0, a0);
  }
#undef GBODY

  *reinterpret_cast<f32x4*>(&red[wid][lane][0]) = D;
  __syncthreads();

  if (t < 128) {
    const int r = t >> 4, cc = t & 15;
    const int ln = (r >> 2) * 16 + cc, rg = r & 3;
    float v = red[0][ln][rg] + red[1][ln][rg] + red[2][ln][rg] + red[3][ln][rg];
    const int o = blockIdx.x * 16 + cc;
    v += (mode == 2) ? bF[o] : dec16(b16[o], mode);
    const size_t idx = (size_t)r * O_TOT + o;
    if (mode == 0)      ((__hip_bfloat16*)outv)[idx] = __float2bfloat16(v);
    else if (mode == 1) { union { uint16_t u; _Float16 h; } cv; cv.h = (_Float16)v;
                          ((uint16_t*)outv)[idx] = cv.u; }
    else                ((float*)outv)[idx] = v;
  }
}

// --- verified R4 fallback (used only if ws too small) ---
static constexpr int NTHR = 512, O_PER_IT = 2, ITERS = 14, NBLK = 1024;
__global__ __launch_bounds__(NTHR, 1)
void wq_fallback_kernel(const uint16_t* __restrict__ x16,
                        const uint32_t* __restrict__ qweight,
                        const uint32_t* __restrict__ qzeros,
                        const uint16_t* __restrict__ sc16,
                        const uint16_t* __restrict__ b16,
                        void* __restrict__ outv,
                        const int* __restrict__ flag)
{
  __shared__ float lds[O_PER_IT][M_ROWS][NTHR];
  const int mode = *flag;
  const int t = threadIdx.x;
  const float* xF  = (const float*)x16;
  const float* scF = (const float*)sc16;
  const float* bF  = (const float*)b16;
  float xf[M_ROWS][16];
  {
    const int kbase = 16 * t;
    if (mode == 2) {
      #pragma unroll
      for (int n = 0; n < M_ROWS; ++n)
        #pragma unroll
        for (int i = 0; i < 16; ++i) xf[n][i] = xF[(size_t)n * K_TOT + kbase + i];
    } else {
      #pragma unroll
      for (int n = 0; n < M_ROWS; ++n)
        #pragma unroll
        for (int i = 0; i < 16; ++i) xf[n][i] = dec16(x16[(size_t)n * K_TOT + kbase + i], mode);
    }
  }
  const int g = t >> 3, zsh = (g & 7) * 4, zword = g >> 3;
  for (int it = 0; it < ITERS; ++it) {
    const int obase = blockIdx.x * (ITERS * O_PER_IT) + it * O_PER_IT;
    #pragma unroll
    for (int oi = 0; oi < O_PER_IT; ++oi) {
      const int o = obase + oi;
      const uint32_t zw = qzeros[o * 8 + zword];
      const float z = (float)((zw >> zsh) & 15u);
      const float s = (mode == 2) ? scF[o * 64 + g] : dec16(sc16[o * 64 + g], mode);
      const uint32_t w0 = qweight[(size_t)o * KW + 2 * t];
      const uint32_t w1 = qweight[(size_t)o * KW + 2 * t + 1];
      float d[M_ROWS];
      #pragma unroll
      for (int n = 0; n < M_ROWS; ++n) d[n] = 0.f;
      const uint32_t wv[2] = { w0, w1 };
      #pragma unroll
      for (int w = 0; w < 2; ++w)
        #pragma unroll
        for (int j = 0; j < 8; ++j) {
          const float q = (float)((wv[w] >> (4 * j)) & 15u);
          const float wgt = s * (q - z);
          #pragma unroll
          for (int n = 0; n < M_ROWS; ++n) d[n] = fmaf(wgt, xf[n][8 * w + j], d[n]);
        }
      #pragma unroll
      for (int n = 0; n < M_ROWS; ++n) lds[oi][n][t] = d[n];
    }
    __syncthreads();
    {
      const int wvid = t >> 6, lanei = t & 63;
      #pragma unroll
      for (int cc2 = 0; cc2 < 2; ++cc2) {
        const int p = 2 * wvid + cc2, oi = p >> 3, n = p & 7;
        float v = 0.f;
        #pragma unroll
        for (int i = 0; i < 8; ++i) v += lds[oi][n][lanei + 64 * i];
        v += __shfl_xor(v, 32); v += __shfl_xor(v, 16); v += __shfl_xor(v, 8);
        v += __shfl_xor(v, 4);  v += __shfl_xor(v, 2);  v += __shfl_xor(v, 1);
        if (lanei == 0) {
          const int o = obase + oi;
          const float b = (mode == 2) ? bF[o] : dec16(b16[o], mode);
          const float r = v + b;
          const size_t idx = (size_t)n * O_TOT + o;
          if (mode == 0)      ((__hip_bfloat16*)outv)[idx] = __float2bfloat16(r);
          else if (mode == 1) { union { uint16_t u; _Float16 h; } cc; cc.h = (_Float16)r;
                                ((uint16_t*)outv)[idx] = cc.u; }
          else                ((float*)outv)[idx] = r;
        }
      }
    }
    __syncthreads();
  }
}

extern "C" void kernel_launch(void* const* d_in, const int* in_sizes, int n_in,
                              void* d_out, int out_size, void* d_ws, size_t ws_size,
                              hipStream_t stream)
{
  const uint16_t* x       = (const uint16_t*)d_in[0];
  const uint32_t* qweight = (const uint32_t*)d_in[1];
  const uint32_t* qzeros  = (const uint32_t*)d_in[2];
  const uint16_t* scales  = (const uint16_t*)d_in[3];
  const uint16_t* bias    = (const uint16_t*)d_in[4];
  int* flag = (int*)d_ws;

  hipLaunchKernelGGL(sniff_kernel, dim3(1), dim3(64), 0, stream, x, flag);

  if (ws_size >= WS_NEED) {
    uint8_t* ws = (uint8_t*)d_ws;
    hipLaunchKernelGGL(prep_kernel, dim3(32), dim3(256), 0, stream, x, ws, flag);
    hipLaunchKernelGGL(wq_mfma_kernel, dim3(1792), dim3(256), 0, stream,
                       qweight, qzeros, scales, bias, d_out, ws, flag);
  } else {
    hipLaunchKernelGGL(wq_fallback_kernel, dim3(NBLK), dim3(NTHR), 0, stream,
                       x, qweight, qzeros, scales, bias, d_out, flag);
  }
}

// Round 8
// 47.281 us; speedup vs baseline: 4.4722x; 1.9919x over previous
//
#include <hip/hip_runtime.h>
#include <hip/hip_bf16.h>
#include <stdint.h>

typedef short short8 __attribute__((ext_vector_type(8)));
typedef float f32x4  __attribute__((ext_vector_type(4)));

static constexpr int O_TOT = 28672;
static constexpr int K_TOT = 8192;
static constexpr int M_ROWS = 8;
static constexpr int KW = 1024;            // packed int32 words per output row

// workspace layout
static constexpr size_t WS_X     = 4096;                         // 8 rows x 8192 bf16 = 128KB
static constexpr size_t WS_SG    = WS_X + (size_t)8 * K_TOT * 2; // 64 groups x 8 rows f32 = 2KB
static constexpr size_t WS_PART  = WS_SG + 64 * 8 * 4;           // [4][8][28672] f32 = 3.67MB
static constexpr size_t WS_NEED_V8 = WS_PART + (size_t)4 * 8 * O_TOT * 4 + 64;
static constexpr size_t WS_NEED_R7 = WS_PART + 64;

// mode: 0 = bf16, 1 = fp16, 2 = f32
__device__ __forceinline__ float dec16(uint16_t u, int mode) {
  if (mode == 0) {
    union { uint32_t i; float f; } v; v.i = ((uint32_t)u) << 16; return v.f;
  } else {
    union { uint16_t u; _Float16 h; } v; v.u = u; return (float)v.h;
  }
}
__device__ __forceinline__ uint16_t f2bf_bits(float f) {
  union { __hip_bfloat16 b; uint16_t u; } v; v.b = __float2bfloat16(f); return v.u;
}
__device__ __forceinline__ uint16_t f2h_bits(float f) {
  union { uint16_t u; _Float16 h; } v; v.h = (_Float16)f; return v.u;
}

// --- dtype sniffer (verified R5-R7) ---
__global__ void sniff_kernel(const uint16_t* __restrict__ x, int* __restrict__ flag) {
  const int t = threadIdx.x;
  int ce = 0, co = 0;
  #pragma unroll
  for (int i = 0; i < 2; ++i) {
    const uint4 u = *reinterpret_cast<const uint4*>(x + (size_t)(t + 64 * i) * 8);
    const uint32_t d[4] = {u.x, u.y, u.z, u.w};
    #pragma unroll
    for (int j = 0; j < 4; ++j) {
      const int elo = (d[j] >> 7)  & 0xFF;
      const int ehi = (d[j] >> 23) & 0xFF;
      ce += (elo >= 118 && elo <= 131);
      co += (ehi >= 118 && ehi <= 131);
    }
  }
  for (int d = 32; d; d >>= 1) { ce += __shfl_xor(ce, d); co += __shfl_xor(co, d); }
  if (t == 0) {
    int mode;
    if (ce > 358 && co > 358)      mode = 0;   // bf16
    else if (co > 358)             mode = 2;   // f32
    else                           mode = 1;   // fp16
    *flag = mode;
  }
}

// --- prep: decode x rows 0..7 -> bf16 ws (permuted 0,4,1,5,2,6,3,7 per 8-block)
//     + fused per-(group,row) sums of the STAGED bf16 values (verified R7) ---
__global__ __launch_bounds__(256)
void prep_kernel(const uint16_t* __restrict__ x16, uint8_t* __restrict__ ws,
                 const int* __restrict__ flag) {
  __shared__ float psum[256];
  const int mode = *flag;
  const int t = threadIdx.x;
  const int tid = blockIdx.x * 256 + t;             // 32 blocks x 256 = 8192
  const int r = tid >> 10, wb = tid & 1023;
  uint16_t s[8];
  if (mode == 2) {
    const float* xF = (const float*)x16;
    #pragma unroll
    for (int j = 0; j < 8; ++j) s[j] = f2bf_bits(xF[(size_t)r * K_TOT + wb * 8 + j]);
  } else {
    const uint4 u = *reinterpret_cast<const uint4*>(x16 + (size_t)r * K_TOT + wb * 8);
    const uint32_t d[4] = {u.x, u.y, u.z, u.w};
    #pragma unroll
    for (int j = 0; j < 8; ++j) {
      const uint16_t raw = (j & 1) ? (uint16_t)(d[j >> 1] >> 16) : (uint16_t)(d[j >> 1] & 0xffffu);
      s[j] = (mode == 0) ? raw : f2bf_bits(dec16(raw, 1));
    }
  }
  uint16_t p[8];
  p[0] = s[0]; p[1] = s[4]; p[2] = s[1]; p[3] = s[5];
  p[4] = s[2]; p[5] = s[6]; p[6] = s[3]; p[7] = s[7];
  uint4 o;
  o.x = (uint32_t)p[0] | ((uint32_t)p[1] << 16);
  o.y = (uint32_t)p[2] | ((uint32_t)p[3] << 16);
  o.z = (uint32_t)p[4] | ((uint32_t)p[5] << 16);
  o.w = (uint32_t)p[6] | ((uint32_t)p[7] << 16);
  *reinterpret_cast<uint4*>((uint16_t*)(ws + WS_X) + (size_t)r * K_TOT + wb * 8) = o;

  float loc = 0.f;
  #pragma unroll
  for (int j = 0; j < 8; ++j) loc += dec16(p[j], 0);
  psum[t] = loc;
  __syncthreads();
  #pragma unroll
  for (int st = 8; st; st >>= 1) {
    if ((t & 15) < st) psum[t] += psum[t + st];
    __syncthreads();
  }
  if ((t & 15) == 0) {
    const int g = t >> 4;
    const int G = (blockIdx.x & 3) * 16 + g;
    ((float*)(ws + WS_SG))[G * 8 + r] = psum[t];
  }
}

// --- v8 main: block = (col-tile, k-quarter); x-quarter in LDS; 16-deep q prefetch ---
__global__ __launch_bounds__(256)
void wq_mfma2_kernel(const uint32_t* __restrict__ qweight,
                     const uint32_t* __restrict__ qzeros,
                     const uint16_t* __restrict__ sc16,
                     const uint8_t* __restrict__ ws,
                     float* __restrict__ part,
                     const int* __restrict__ flag)
{
  __shared__ __align__(16) uint4 xl[8 * 257];   // 32.9KB: 8 rows x 256 uint4, pad 1/row
  __shared__ __align__(16) float sgl[16 * 8];   // group sums for this quarter
  const int mode = *flag;
  const float* scF = (const float*)sc16;
  const int t = threadIdx.x, wid = t >> 6, lane = t & 63;
  const int c = lane & 15, g4 = lane >> 4;
  const int bi = blockIdx.x;
  const int ct = bi % 448, kq = bi / 448;       // col-tile, k-quarter
  const int cg = ct * 64 + wid * 16 + c;        // this lane's output column

  // stage x quarter: 2048 uint4 from ws into padded LDS rows
  {
    const uint4* src = (const uint4*)(ws + WS_X);
    #pragma unroll
    for (int j = 0; j < 8; ++j) {
      const int idx = j * 256 + t;
      const int r = idx >> 8, w = idx & 255;
      xl[r * 257 + w] = src[(size_t)r * 1024 + kq * 256 + w];
    }
    if (t < 128) {
      const int G = t >> 3, r = t & 7;
      sgl[G * 8 + r] = ((const float*)(ws + WS_SG))[(kq * 16 + G) * 8 + r];
    }
  }

  // preload metadata to registers
  const uint2 qz = *reinterpret_cast<const uint2*>(qzeros + cg * 8 + kq * 2);
  float sv[16];
  #pragma unroll
  for (int G = 0; G < 16; ++G)
    sv[G] = (mode == 2) ? scF[cg * 64 + kq * 16 + G]
                        : dec16(sc16[cg * 64 + kq * 16 + G], mode);

  __syncthreads();

  // issue ALL 16 qweight loads up-front (max MLP; the only in-loop HBM stream)
  const uint32_t* qp = qweight + (size_t)cg * KW + kq * 256;
  uint4 q[16];
  #pragma unroll
  for (int T = 0; T < 16; ++T)
    q[T] = *reinterpret_cast<const uint4*>(qp + 16 * T + 4 * g4);

  f32x4 D = {0.f, 0.f, 0.f, 0.f};
  #pragma unroll
  for (int T = 0; T < 16; ++T) {
    const uint4 a0 = xl[(c & 7) * 257 + 16 * T + 4 * g4 + 0];
    const uint4 a1 = xl[(c & 7) * 257 + 16 * T + 4 * g4 + 1];
    const uint4 a2 = xl[(c & 7) * 257 + 16 * T + 4 * g4 + 2];
    const uint4 a3 = xl[(c & 7) * 257 + 16 * T + 4 * g4 + 3];
    const f32x4 sgv = *reinterpret_cast<const f32x4*>(&sgl[T * 8 + (g4 & 1) * 4]);

    f32x4 tmp = {0.f, 0.f, 0.f, 0.f};
    const uint32_t wv[4] = {q[T].x, q[T].y, q[T].z, q[T].w};
    const uint4   av[4] = {a0, a1, a2, a3};
    #pragma unroll
    for (int u = 0; u < 4; ++u) {
      union { uint32_t d[4]; short8 s; } bb;
      bb.d[0] = ( wv[u]        & 0x000F000Fu) | 0x43004300u;
      bb.d[1] = ((wv[u] >> 4)  & 0x000F000Fu) | 0x43004300u;
      bb.d[2] = ((wv[u] >> 8)  & 0x000F000Fu) | 0x43004300u;
      bb.d[3] = ((wv[u] >> 12) & 0x000F000Fu) | 0x43004300u;
      union { uint4 q; short8 s; } aa; aa.q = av[u];
      tmp = __builtin_amdgcn_mfma_f32_16x16x32_bf16(aa.s, bb.s, tmp, 0, 0, 0);
    }
    const uint32_t zraw = (T < 8) ? qz.x : qz.y;
    const float zf = (float)((zraw >> ((T & 7) * 4)) & 15u);
    const float c128z = 128.0f + zf;
    D[0] += sv[T] * (tmp[0] - c128z * sgv[0]);
    D[1] += sv[T] * (tmp[1] - c128z * sgv[1]);
    D[2] += sv[T] * (tmp[2] - c128z * sgv[2]);
    D[3] += sv[T] * (tmp[3] - c128z * sgv[3]);
  }

  if (g4 < 2) {
    #pragma unroll
    for (int reg = 0; reg < 4; ++reg) {
      const int r = g4 * 4 + reg;               // D row = (lane>>4)*4 + reg (m89)
      part[((size_t)kq * 8 + r) * O_TOT + cg] = D[reg];
    }
  }
}

// --- reduce: sum 4 k-quarter partials + bias -> output ---
__global__ __launch_bounds__(256)
void reduce_kernel(const float* __restrict__ part,
                   const uint16_t* __restrict__ b16,
                   void* __restrict__ outv,
                   const int* __restrict__ flag)
{
  const int mode = *flag;
  const int idx = blockIdx.x * 256 + threadIdx.x;  // 224 blocks: 57344 threads
  const int lin = idx * 4;                          // 4 consecutive o of one row
  const int r = lin / O_TOT, o = lin - r * O_TOT;
  f32x4 s = {0.f, 0.f, 0.f, 0.f};
  #pragma unroll
  for (int k = 0; k < 4; ++k) {
    const f32x4 p = *reinterpret_cast<const f32x4*>(part + ((size_t)k * 8 + r) * O_TOT + o);
    s[0] += p[0]; s[1] += p[1]; s[2] += p[2]; s[3] += p[3];
  }
  if (mode == 2) {
    const float* bF = (const float*)b16;
    const f32x4 b = *reinterpret_cast<const f32x4*>(bF + o);
    f32x4 w = {s[0] + b[0], s[1] + b[1], s[2] + b[2], s[3] + b[3]};
    *reinterpret_cast<f32x4*>((float*)outv + (size_t)r * O_TOT + o) = w;
  } else {
    const uint2 bb = *reinterpret_cast<const uint2*>(b16 + o);
    const uint16_t bu[4] = {(uint16_t)(bb.x & 0xffffu), (uint16_t)(bb.x >> 16),
                            (uint16_t)(bb.y & 0xffffu), (uint16_t)(bb.y >> 16)};
    uint16_t w[4];
    #pragma unroll
    for (int j = 0; j < 4; ++j) {
      const float v = s[j] + dec16(bu[j], mode);
      w[j] = (mode == 0) ? f2bf_bits(v) : f2h_bits(v);
    }
    uint2 pk;
    pk.x = (uint32_t)w[0] | ((uint32_t)w[1] << 16);
    pk.y = (uint32_t)w[2] | ((uint32_t)w[3] << 16);
    *reinterpret_cast<uint2*>((uint16_t*)outv + (size_t)r * O_TOT + o) = pk;
  }
}

// --- R7 main (verified, 90us) as mid-tier fallback ---
__global__ __launch_bounds__(256)
void wq_mfma_kernel(const uint32_t* __restrict__ qweight,
                    const uint32_t* __restrict__ qzeros,
                    const uint16_t* __restrict__ sc16,
                    const uint16_t* __restrict__ b16,
                    void* __restrict__ outv,
                    const uint8_t* __restrict__ ws,
                    const int* __restrict__ flag)
{
  __shared__ float red[4][64][4];
  const int mode = *flag;
  const float* scF = (const float*)sc16;
  const float* bF  = (const float*)b16;
  const int t = threadIdx.x, wid = t >> 6, lane = t & 63;
  const int c = lane & 15, g4 = lane >> 4;
  const int cg = blockIdx.x * 16 + c;

  const uint16_t* xb  = (const uint16_t*)(ws + WS_X);
  const float*    sgp = (const float*)(ws + WS_SG);
  const uint32_t* qp  = qweight + (size_t)cg * KW;
  const uint4*  abase = (const uint4*)(xb + (size_t)(c & 7) * K_TOT);
  const int G0   = wid * 16;
  const int boff = 4 * g4;
  const uint2 qz = *reinterpret_cast<const uint2*>(qzeros + cg * 8 + wid * 2);

  f32x4 D = {0.f, 0.f, 0.f, 0.f};
  uint4 q0 = *reinterpret_cast<const uint4*>(qp + 16 * G0 + boff);
  uint4 a0[4], a1[4]; uint4 q1;
  #pragma unroll
  for (int u = 0; u < 4; ++u) a0[u] = abase[16 * G0 + boff + u];

#define GBODY(TT, QC, AC, QN, AN)                                              \
  do {                                                                         \
    const int Gc = G0 + (TT);                                                  \
    const int Gn = (Gc + 1 <= 63) ? Gc + 1 : 63;                               \
    QN = *reinterpret_cast<const uint4*>(qp + 16 * Gn + boff);                 \
    AN[0] = abase[16 * Gn + boff + 0];                                         \
    AN[1] = abase[16 * Gn + boff + 1];                                         \
    AN[2] = abase[16 * Gn + boff + 2];                                         \
    AN[3] = abase[16 * Gn + boff + 3];                                         \
    f32x4 tmp = {0.f, 0.f, 0.f, 0.f};                                          \
    const uint32_t wv[4] = {QC.x, QC.y, QC.z, QC.w};                           \
    _Pragma("unroll")                                                          \
    for (int u = 0; u < 4; ++u) {                                              \
      union { uint32_t d[4]; short8 s; } bb;                                   \
      bb.d[0] = ( wv[u]        & 0x000F000Fu) | 0x43004300u;                   \
      bb.d[1] = ((wv[u] >> 4)  & 0x000F000Fu) | 0x43004300u;                   \
      bb.d[2] = ((wv[u] >> 8)  & 0x000F000Fu) | 0x43004300u;                   \
      bb.d[3] = ((wv[u] >> 12) & 0x000F000Fu) | 0x43004300u;                   \
      union { uint4 q; short8 s; } aa; aa.q = AC[u];                           \
      tmp = __builtin_amdgcn_mfma_f32_16x16x32_bf16(aa.s, bb.s, tmp, 0, 0, 0); \
    }                                                                          \
    const uint32_t zraw = ((TT) < 8) ? qz.x : qz.y;                            \
    const float zf = (float)((zraw >> (((TT) & 7) * 4)) & 15u);                \
    const float sv2 = (mode == 2) ? scF[cg * 64 + Gc]                          \
                                  : dec16(sc16[cg * 64 + Gc], mode);           \
    const f32x4 sgv = *reinterpret_cast<const f32x4*>(sgp + Gc * 8 + (g4 & 1) * 4); \
    const float c128z = 128.0f + zf;                                           \
    D[0] += sv2 * (tmp[0] - c128z * sgv[0]);                                   \
    D[1] += sv2 * (tmp[1] - c128z * sgv[1]);                                   \
    D[2] += sv2 * (tmp[2] - c128z * sgv[2]);                                   \
    D[3] += sv2 * (tmp[3] - c128z * sgv[3]);                                   \
  } while (0)

  for (int T = 0; T < 16; T += 2) {
    GBODY(T,     q0, a0, q1, a1);
    GBODY(T + 1, q1, a1, q0, a0);
  }
#undef GBODY

  *reinterpret_cast<f32x4*>(&red[wid][lane][0]) = D;
  __syncthreads();

  if (t < 128) {
    const int r = t >> 4, cc = t & 15;
    const int ln = (r >> 2) * 16 + cc, rg = r & 3;
    float v = red[0][ln][rg] + red[1][ln][rg] + red[2][ln][rg] + red[3][ln][rg];
    const int o = blockIdx.x * 16 + cc;
    v += (mode == 2) ? bF[o] : dec16(b16[o], mode);
    const size_t idx = (size_t)r * O_TOT + o;
    if (mode == 0)      ((__hip_bfloat16*)outv)[idx] = __float2bfloat16(v);
    else if (mode == 1) { union { uint16_t u; _Float16 h; } cv; cv.h = (_Float16)v;
                          ((uint16_t*)outv)[idx] = cv.u; }
    else                ((float*)outv)[idx] = v;
  }
}

// --- R4 scalar fallback (ws too small for anything) ---
static constexpr int NTHR = 512, O_PER_IT = 2, ITERS = 14, NBLK = 1024;
__global__ __launch_bounds__(NTHR, 1)
void wq_fallback_kernel(const uint16_t* __restrict__ x16,
                        const uint32_t* __restrict__ qweight,
                        const uint32_t* __restrict__ qzeros,
                        const uint16_t* __restrict__ sc16,
                        const uint16_t* __restrict__ b16,
                        void* __restrict__ outv,
                        const int* __restrict__ flag)
{
  __shared__ float lds[O_PER_IT][M_ROWS][NTHR];
  const int mode = *flag;
  const int t = threadIdx.x;
  const float* xF  = (const float*)x16;
  const float* scF = (const float*)sc16;
  const float* bF  = (const float*)b16;
  float xf[M_ROWS][16];
  {
    const int kbase = 16 * t;
    if (mode == 2) {
      #pragma unroll
      for (int n = 0; n < M_ROWS; ++n)
        #pragma unroll
        for (int i = 0; i < 16; ++i) xf[n][i] = xF[(size_t)n * K_TOT + kbase + i];
    } else {
      #pragma unroll
      for (int n = 0; n < M_ROWS; ++n)
        #pragma unroll
        for (int i = 0; i < 16; ++i) xf[n][i] = dec16(x16[(size_t)n * K_TOT + kbase + i], mode);
    }
  }
  const int g = t >> 3, zsh = (g & 7) * 4, zword = g >> 3;
  for (int it = 0; it < ITERS; ++it) {
    const int obase = blockIdx.x * (ITERS * O_PER_IT) + it * O_PER_IT;
    #pragma unroll
    for (int oi = 0; oi < O_PER_IT; ++oi) {
      const int o = obase + oi;
      const uint32_t zw = qzeros[o * 8 + zword];
      const float z = (float)((zw >> zsh) & 15u);
      const float s = (mode == 2) ? scF[o * 64 + g] : dec16(sc16[o * 64 + g], mode);
      const uint32_t w0 = qweight[(size_t)o * KW + 2 * t];
      const uint32_t w1 = qweight[(size_t)o * KW + 2 * t + 1];
      float d[M_ROWS];
      #pragma unroll
      for (int n = 0; n < M_ROWS; ++n) d[n] = 0.f;
      const uint32_t wv[2] = { w0, w1 };
      #pragma unroll
      for (int w = 0; w < 2; ++w)
        #pragma unroll
        for (int j = 0; j < 8; ++j) {
          const float q = (float)((wv[w] >> (4 * j)) & 15u);
          const float wgt = s * (q - z);
          #pragma unroll
          for (int n = 0; n < M_ROWS; ++n) d[n] = fmaf(wgt, xf[n][8 * w + j], d[n]);
        }
      #pragma unroll
      for (int n = 0; n < M_ROWS; ++n) lds[oi][n][t] = d[n];
    }
    __syncthreads();
    {
      const int wvid = t >> 6, lanei = t & 63;
      #pragma unroll
      for (int cc2 = 0; cc2 < 2; ++cc2) {
        const int p = 2 * wvid + cc2, oi = p >> 3, n = p & 7;
        float v = 0.f;
        #pragma unroll
        for (int i = 0; i < 8; ++i) v += lds[oi][n][lanei + 64 * i];
        v += __shfl_xor(v, 32); v += __shfl_xor(v, 16); v += __shfl_xor(v, 8);
        v += __shfl_xor(v, 4);  v += __shfl_xor(v, 2);  v += __shfl_xor(v, 1);
        if (lanei == 0) {
          const int o = obase + oi;
          const float b = (mode == 2) ? bF[o] : dec16(b16[o], mode);
          const float r = v + b;
          const size_t idx = (size_t)n * O_TOT + o;
          if (mode == 0)      ((__hip_bfloat16*)outv)[idx] = __float2bfloat16(r);
          else if (mode == 1) { union { uint16_t u; _Float16 h; } cc; cc.h = (_Float16)r;
                                ((uint16_t*)outv)[idx] = cc.u; }
          else                ((float*)outv)[idx] = r;
        }
      }
    }
    __syncthreads();
  }
}

extern "C" void kernel_launch(void* const* d_in, const int* in_sizes, int n_in,
                              void* d_out, int out_size, void* d_ws, size_t ws_size,
                              hipStream_t stream)
{
  const uint16_t* x       = (const uint16_t*)d_in[0];
  const uint32_t* qweight = (const uint32_t*)d_in[1];
  const uint32_t* qzeros  = (const uint32_t*)d_in[2];
  const uint16_t* scales  = (const uint16_t*)d_in[3];
  const uint16_t* bias    = (const uint16_t*)d_in[4];
  int* flag = (int*)d_ws;
  uint8_t* ws = (uint8_t*)d_ws;

  hipLaunchKernelGGL(sniff_kernel, dim3(1), dim3(64), 0, stream, x, flag);

  if (ws_size >= WS_NEED_V8) {
    float* part = (float*)(ws + WS_PART);
    hipLaunchKernelGGL(prep_kernel, dim3(32), dim3(256), 0, stream, x, ws, flag);
    hipLaunchKernelGGL(wq_mfma2_kernel, dim3(1792), dim3(256), 0, stream,
                       qweight, qzeros, scales, ws, part, flag);
    hipLaunchKernelGGL(reduce_kernel, dim3(224), dim3(256), 0, stream,
                       part, bias, d_out, flag);
  } else if (ws_size >= WS_NEED_R7) {
    hipLaunchKernelGGL(prep_kernel, dim3(32), dim3(256), 0, stream, x, ws, flag);
    hipLaunchKernelGGL(wq_mfma_kernel, dim3(1792), dim3(256), 0, stream,
                       qweight, qzeros, scales, bias, d_out, ws, flag);
  } else {
    hipLaunchKernelGGL(wq_fallback_kernel, dim3(NBLK), dim3(NTHR), 0, stream,
                       x, qweight, qzeros, scales, bias, d_out, flag);
  }
}

// Round 9
// 47.074 us; speedup vs baseline: 4.4918x; 1.0044x over previous
//
#include <hip/hip_runtime.h>
#include <hip/hip_bf16.h>
#include <stdint.h>

typedef short short8 __attribute__((ext_vector_type(8)));
typedef float f32x4  __attribute__((ext_vector_type(4)));

static constexpr int O_TOT = 28672;
static constexpr int K_TOT = 8192;
static constexpr int M_ROWS = 8;
static constexpr int KW = 1024;            // packed int32 words per output row

// workspace layout
static constexpr size_t WS_X    = 4096;                           // 8 x 8192 bf16 = 128KB
static constexpr size_t WS_SG   = WS_X + (size_t)8 * K_TOT * 2;   // 64x8 f32 = 2KB
static constexpr size_t WS_SCT  = WS_SG + 64 * 8 * 4;             // f32 [64][28672] = 7.34MB
static constexpr size_t WS_PART = WS_SCT + (size_t)64 * O_TOT * 4;// f32 [8][8][28672] = 7.34MB
static constexpr size_t WS_NEED_V9 = WS_PART + (size_t)8 * 8 * O_TOT * 4 + 64;
static constexpr size_t WS_NEED_R7 = WS_SG + 64 * 8 * 4 + 64;

// mode: 0 = bf16, 1 = fp16, 2 = f32
__device__ __forceinline__ float dec16(uint16_t u, int mode) {
  if (mode == 0) {
    union { uint32_t i; float f; } v; v.i = ((uint32_t)u) << 16; return v.f;
  } else {
    union { uint16_t u; _Float16 h; } v; v.u = u; return (float)v.h;
  }
}
__device__ __forceinline__ uint16_t f2bf_bits(float f) {
  union { __hip_bfloat16 b; uint16_t u; } v; v.b = __float2bfloat16(f); return v.u;
}
__device__ __forceinline__ uint16_t f2h_bits(float f) {
  union { uint16_t u; _Float16 h; } v; v.h = (_Float16)f; return v.u;
}

// --- dtype sniffer (verified R5-R8) ---
__global__ void sniff_kernel(const uint16_t* __restrict__ x, int* __restrict__ flag) {
  const int t = threadIdx.x;
  int ce = 0, co = 0;
  #pragma unroll
  for (int i = 0; i < 2; ++i) {
    const uint4 u = *reinterpret_cast<const uint4*>(x + (size_t)(t + 64 * i) * 8);
    const uint32_t d[4] = {u.x, u.y, u.z, u.w};
    #pragma unroll
    for (int j = 0; j < 4; ++j) {
      const int elo = (d[j] >> 7)  & 0xFF;
      const int ehi = (d[j] >> 23) & 0xFF;
      ce += (elo >= 118 && elo <= 131);
      co += (ehi >= 118 && ehi <= 131);
    }
  }
  for (int d = 32; d; d >>= 1) { ce += __shfl_xor(ce, d); co += __shfl_xor(co, d); }
  if (t == 0) {
    int mode;
    if (ce > 358 && co > 358)      mode = 0;   // bf16
    else if (co > 358)             mode = 2;   // f32
    else                           mode = 1;   // fp16
    *flag = mode;
  }
}

// --- prep: decode x rows 0..7 -> bf16 ws (permuted 0,4,1,5,2,6,3,7 per 8-block)
//     + fused per-(group,row) sums of the STAGED bf16 values (verified R7/R8) ---
__global__ __launch_bounds__(256)
void prep_kernel(const uint16_t* __restrict__ x16, uint8_t* __restrict__ ws,
                 const int* __restrict__ flag) {
  __shared__ float psum[256];
  const int mode = *flag;
  const int t = threadIdx.x;
  const int tid = blockIdx.x * 256 + t;             // 32 blocks x 256 = 8192
  const int r = tid >> 10, wb = tid & 1023;
  uint16_t s[8];
  if (mode == 2) {
    const float* xF = (const float*)x16;
    #pragma unroll
    for (int j = 0; j < 8; ++j) s[j] = f2bf_bits(xF[(size_t)r * K_TOT + wb * 8 + j]);
  } else {
    const uint4 u = *reinterpret_cast<const uint4*>(x16 + (size_t)r * K_TOT + wb * 8);
    const uint32_t d[4] = {u.x, u.y, u.z, u.w};
    #pragma unroll
    for (int j = 0; j < 8; ++j) {
      const uint16_t raw = (j & 1) ? (uint16_t)(d[j >> 1] >> 16) : (uint16_t)(d[j >> 1] & 0xffffu);
      s[j] = (mode == 0) ? raw : f2bf_bits(dec16(raw, 1));
    }
  }
  uint16_t p[8];
  p[0] = s[0]; p[1] = s[4]; p[2] = s[1]; p[3] = s[5];
  p[4] = s[2]; p[5] = s[6]; p[6] = s[3]; p[7] = s[7];
  uint4 o;
  o.x = (uint32_t)p[0] | ((uint32_t)p[1] << 16);
  o.y = (uint32_t)p[2] | ((uint32_t)p[3] << 16);
  o.z = (uint32_t)p[4] | ((uint32_t)p[5] << 16);
  o.w = (uint32_t)p[6] | ((uint32_t)p[7] << 16);
  *reinterpret_cast<uint4*>((uint16_t*)(ws + WS_X) + (size_t)r * K_TOT + wb * 8) = o;

  float loc = 0.f;
  #pragma unroll
  for (int j = 0; j < 8; ++j) loc += dec16(p[j], 0);
  psum[t] = loc;
  __syncthreads();
  #pragma unroll
  for (int st = 8; st; st >>= 1) {
    if ((t & 15) < st) psum[t] += psum[t + st];
    __syncthreads();
  }
  if ((t & 15) == 0) {
    const int g = t >> 4;
    const int G = (blockIdx.x & 3) * 16 + g;
    ((float*)(ws + WS_SG))[G * 8 + r] = psum[t];
  }
}

// --- sct: transpose scales [O][64] -> f32 [64][O] (coalesced main-kernel reads) ---
__global__ __launch_bounds__(256)
void sct_kernel(const uint16_t* __restrict__ sc16, uint8_t* __restrict__ ws,
                const int* __restrict__ flag) {
  __shared__ float tile[64][65];
  const int mode = *flag;
  const int b = blockIdx.x, t = threadIdx.x;        // 448 blocks: o-tile of 64
  const float* scF = (const float*)sc16;
  #pragma unroll
  for (int i = 0; i < 16; ++i) {
    const int idx = i * 256 + t;
    const int oo = idx >> 6, gg = idx & 63;
    tile[oo][gg] = (mode == 2) ? scF[(size_t)(b * 64 + oo) * 64 + gg]
                               : dec16(sc16[(size_t)(b * 64 + oo) * 64 + gg], mode);
  }
  __syncthreads();
  float* sct = (float*)(ws + WS_SCT);
  #pragma unroll
  for (int i = 0; i < 16; ++i) {
    const int idx = i * 256 + t;
    const int gg = idx >> 6, oo = idx & 63;
    sct[(size_t)gg * O_TOT + b * 64 + oo] = tile[oo][gg];
  }
}

// --- v9 main: block = (col-tile, k-eighth), kq FAST in blockIdx (streaming sweep);
//     x-chunk in LDS; 8-deep q prefetch; coalesced f32 scale reads ---
__global__ __launch_bounds__(256)
void wq_mfma3_kernel(const uint32_t* __restrict__ qweight,
                     const uint32_t* __restrict__ qzeros,
                     const uint8_t* __restrict__ ws,
                     float* __restrict__ part)
{
  __shared__ __align__(16) uint4 xl[8 * 129];   // 16.5KB
  __shared__ float sgl[64];
  const int t = threadIdx.x, wid = t >> 6, lane = t & 63;
  const int c = lane & 15, g4 = lane >> 4;
  const int bi = blockIdx.x;
  const int ct = bi >> 3, kq = bi & 7;          // kq fast: full-coverage sweep
  const int cg = ct * 64 + wid * 16 + c;

  // stage x chunk (1024 uint4) + group sums (64 f32, contiguous)
  {
    const uint4* src = (const uint4*)(ws + WS_X);
    #pragma unroll
    for (int j = 0; j < 4; ++j) {
      const int idx = j * 256 + t;
      const int r = idx >> 7, w = idx & 127;
      xl[r * 129 + w] = src[(size_t)r * 1024 + kq * 128 + w];
    }
    if (t < 64) sgl[t] = ((const float*)(ws + WS_SG))[kq * 64 + t];
  }

  const uint32_t qzw = qzeros[cg * 8 + kq];     // all 8 zeros of this chunk
  const float* sct = (const float*)(ws + WS_SCT);
  float sv[8];
  #pragma unroll
  for (int T = 0; T < 8; ++T)
    sv[T] = sct[(size_t)(kq * 8 + T) * O_TOT + cg];   // coalesced

  __syncthreads();

  // issue ALL 8 qweight loads up-front
  const uint32_t* qp = qweight + (size_t)cg * KW + kq * 128;
  uint4 q[8];
  #pragma unroll
  for (int T = 0; T < 8; ++T)
    q[T] = *reinterpret_cast<const uint4*>(qp + 16 * T + 4 * g4);

  f32x4 D = {0.f, 0.f, 0.f, 0.f};
  #pragma unroll
  for (int T = 0; T < 8; ++T) {
    const uint4 a0 = xl[(c & 7) * 129 + 16 * T + 4 * g4 + 0];
    const uint4 a1 = xl[(c & 7) * 129 + 16 * T + 4 * g4 + 1];
    const uint4 a2 = xl[(c & 7) * 129 + 16 * T + 4 * g4 + 2];
    const uint4 a3 = xl[(c & 7) * 129 + 16 * T + 4 * g4 + 3];
    const f32x4 sgv = *reinterpret_cast<const f32x4*>(&sgl[T * 8 + (g4 & 1) * 4]);

    f32x4 tmp = {0.f, 0.f, 0.f, 0.f};
    const uint32_t wv[4] = {q[T].x, q[T].y, q[T].z, q[T].w};
    const uint4   av[4] = {a0, a1, a2, a3};
    #pragma unroll
    for (int u = 0; u < 4; ++u) {
      union { uint32_t d[4]; short8 s; } bb;
      bb.d[0] = ( wv[u]        & 0x000F000Fu) | 0x43004300u;
      bb.d[1] = ((wv[u] >> 4)  & 0x000F000Fu) | 0x43004300u;
      bb.d[2] = ((wv[u] >> 8)  & 0x000F000Fu) | 0x43004300u;
      bb.d[3] = ((wv[u] >> 12) & 0x000F000Fu) | 0x43004300u;
      union { uint4 q; short8 s; } aa; aa.q = av[u];
      tmp = __builtin_amdgcn_mfma_f32_16x16x32_bf16(aa.s, bb.s, tmp, 0, 0, 0);
    }
    const float zf = (float)((qzw >> (T * 4)) & 15u);
    const float c128z = 128.0f + zf;
    D[0] += sv[T] * (tmp[0] - c128z * sgv[0]);
    D[1] += sv[T] * (tmp[1] - c128z * sgv[1]);
    D[2] += sv[T] * (tmp[2] - c128z * sgv[2]);
    D[3] += sv[T] * (tmp[3] - c128z * sgv[3]);
  }

  if (g4 < 2) {
    #pragma unroll
    for (int reg = 0; reg < 4; ++reg) {
      const int r = g4 * 4 + reg;               // D row = (lane>>4)*4 + reg (m89)
      part[((size_t)kq * 8 + r) * O_TOT + cg] = D[reg];
    }
  }
}

// --- reduce: sum 8 k-chunk partials + bias -> output ---
__global__ __launch_bounds__(256)
void reduce_kernel(const float* __restrict__ part,
                   const uint16_t* __restrict__ b16,
                   void* __restrict__ outv,
                   const int* __restrict__ flag)
{
  const int mode = *flag;
  const int idx = blockIdx.x * 256 + threadIdx.x;  // 224 blocks: 57344 threads
  const int lin = idx * 4;
  const int r = lin / O_TOT, o = lin - r * O_TOT;
  f32x4 s = {0.f, 0.f, 0.f, 0.f};
  #pragma unroll
  for (int k = 0; k < 8; ++k) {
    const f32x4 p = *reinterpret_cast<const f32x4*>(part + ((size_t)k * 8 + r) * O_TOT + o);
    s[0] += p[0]; s[1] += p[1]; s[2] += p[2]; s[3] += p[3];
  }
  if (mode == 2) {
    const float* bF = (const float*)b16;
    const f32x4 b = *reinterpret_cast<const f32x4*>(bF + o);
    f32x4 w = {s[0] + b[0], s[1] + b[1], s[2] + b[2], s[3] + b[3]};
    *reinterpret_cast<f32x4*>((float*)outv + (size_t)r * O_TOT + o) = w;
  } else {
    const uint2 bb = *reinterpret_cast<const uint2*>(b16 + o);
    const uint16_t bu[4] = {(uint16_t)(bb.x & 0xffffu), (uint16_t)(bb.x >> 16),
                            (uint16_t)(bb.y & 0xffffu), (uint16_t)(bb.y >> 16)};
    uint16_t w[4];
    #pragma unroll
    for (int j = 0; j < 4; ++j) {
      const float v = s[j] + dec16(bu[j], mode);
      w[j] = (mode == 0) ? f2bf_bits(v) : f2h_bits(v);
    }
    uint2 pk;
    pk.x = (uint32_t)w[0] | ((uint32_t)w[1] << 16);
    pk.y = (uint32_t)w[2] | ((uint32_t)w[3] << 16);
    *reinterpret_cast<uint2*>((uint16_t*)outv + (size_t)r * O_TOT + o) = pk;
  }
}

// --- R7 main (verified) as mid-tier fallback ---
__global__ __launch_bounds__(256)
void wq_mfma_kernel(const uint32_t* __restrict__ qweight,
                    const uint32_t* __restrict__ qzeros,
                    const uint16_t* __restrict__ sc16,
                    const uint16_t* __restrict__ b16,
                    void* __restrict__ outv,
                    const uint8_t* __restrict__ ws,
                    const int* __restrict__ flag)
{
  __shared__ float red[4][64][4];
  const int mode = *flag;
  const float* scF = (const float*)sc16;
  const float* bF  = (const float*)b16;
  const int t = threadIdx.x, wid = t >> 6, lane = t & 63;
  const int c = lane & 15, g4 = lane >> 4;
  const int cg = blockIdx.x * 16 + c;

  const uint16_t* xb  = (const uint16_t*)(ws + WS_X);
  const float*    sgp = (const float*)(ws + WS_SG);
  const uint32_t* qp  = qweight + (size_t)cg * KW;
  const uint4*  abase = (const uint4*)(xb + (size_t)(c & 7) * K_TOT);
  const int G0   = wid * 16;
  const int boff = 4 * g4;
  const uint2 qz = *reinterpret_cast<const uint2*>(qzeros + cg * 8 + wid * 2);

  f32x4 D = {0.f, 0.f, 0.f, 0.f};
  uint4 q0 = *reinterpret_cast<const uint4*>(qp + 16 * G0 + boff);
  uint4 a0[4], a1[4]; uint4 q1;
  #pragma unroll
  for (int u = 0; u < 4; ++u) a0[u] = abase[16 * G0 + boff + u];

#define GBODY(TT, QC, AC, QN, AN)                                              \
  do {                                                                         \
    const int Gc = G0 + (TT);                                                  \
    const int Gn = (Gc + 1 <= 63) ? Gc + 1 : 63;                               \
    QN = *reinterpret_cast<const uint4*>(qp + 16 * Gn + boff);                 \
    AN[0] = abase[16 * Gn + boff + 0];                                         \
    AN[1] = abase[16 * Gn + boff + 1];                                         \
    AN[2] = abase[16 * Gn + boff + 2];                                         \
    AN[3] = abase[16 * Gn + boff + 3];                                         \
    f32x4 tmp = {0.f, 0.f, 0.f, 0.f};                                          \
    const uint32_t wv[4] = {QC.x, QC.y, QC.z, QC.w};                           \
    _Pragma("unroll")                                                          \
    for (int u = 0; u < 4; ++u) {                                              \
      union { uint32_t d[4]; short8 s; } bb;                                   \
      bb.d[0] = ( wv[u]        & 0x000F000Fu) | 0x43004300u;                   \
      bb.d[1] = ((wv[u] >> 4)  & 0x000F000Fu) | 0x43004300u;                   \
      bb.d[2] = ((wv[u] >> 8)  & 0x000F000Fu) | 0x43004300u;                   \
      bb.d[3] = ((wv[u] >> 12) & 0x000F000Fu) | 0x43004300u;                   \
      union { uint4 q; short8 s; } aa; aa.q = AC[u];                           \
      tmp = __builtin_amdgcn_mfma_f32_16x16x32_bf16(aa.s, bb.s, tmp, 0, 0, 0); \
    }                                                                          \
    const uint32_t zraw = ((TT) < 8) ? qz.x : qz.y;                            \
    const float zf = (float)((zraw >> (((TT) & 7) * 4)) & 15u);                \
    const float sv2 = (mode == 2) ? scF[cg * 64 + Gc]                          \
                                  : dec16(sc16[cg * 64 + Gc], mode);           \
    const f32x4 sgv = *reinterpret_cast<const f32x4*>(sgp + Gc * 8 + (g4 & 1) * 4); \
    const float c128z = 128.0f + zf;                                           \
    D[0] += sv2 * (tmp[0] - c128z * sgv[0]);                                   \
    D[1] += sv2 * (tmp[1] - c128z * sgv[1]);                                   \
    D[2] += sv2 * (tmp[2] - c128z * sgv[2]);                                   \
    D[3] += sv2 * (tmp[3] - c128z * sgv[3]);                                   \
  } while (0)

  for (int T = 0; T < 16; T += 2) {
    GBODY(T,     q0, a0, q1, a1);
    GBODY(T + 1, q1, a1, q0, a0);
  }
#undef GBODY

  *reinterpret_cast<f32x4*>(&red[wid][lane][0]) = D;
  __syncthreads();

  if (t < 128) {
    const int r = t >> 4, cc = t & 15;
    const int ln = (r >> 2) * 16 + cc, rg = r & 3;
    float v = red[0][ln][rg] + red[1][ln][rg] + red[2][ln][rg] + red[3][ln][rg];
    const int o = blockIdx.x * 16 + cc;
    v += (mode == 2) ? bF[o] : dec16(b16[o], mode);
    const size_t idx = (size_t)r * O_TOT + o;
    if (mode == 0)      ((__hip_bfloat16*)outv)[idx] = __float2bfloat16(v);
    else if (mode == 1) { union { uint16_t u; _Float16 h; } cv; cv.h = (_Float16)v;
                          ((uint16_t*)outv)[idx] = cv.u; }
    else                ((float*)outv)[idx] = v;
  }
}

// --- R4 scalar fallback ---
static constexpr int NTHR = 512, O_PER_IT = 2, ITERS = 14, NBLK = 1024;
__global__ __launch_bounds__(NTHR, 1)
void wq_fallback_kernel(const uint16_t* __restrict__ x16,
                        const uint32_t* __restrict__ qweight,
                        const uint32_t* __restrict__ qzeros,
                        const uint16_t* __restrict__ sc16,
                        const uint16_t* __restrict__ b16,
                        void* __restrict__ outv,
                        const int* __restrict__ flag)
{
  __shared__ float lds[O_PER_IT][M_ROWS][NTHR];
  const int mode = *flag;
  const int t = threadIdx.x;
  const float* xF  = (const float*)x16;
  const float* scF = (const float*)sc16;
  const float* bF  = (const float*)b16;
  float xf[M_ROWS][16];
  {
    const int kbase = 16 * t;
    if (mode == 2) {
      #pragma unroll
      for (int n = 0; n < M_ROWS; ++n)
        #pragma unroll
        for (int i = 0; i < 16; ++i) xf[n][i] = xF[(size_t)n * K_TOT + kbase + i];
    } else {
      #pragma unroll
      for (int n = 0; n < M_ROWS; ++n)
        #pragma unroll
        for (int i = 0; i < 16; ++i) xf[n][i] = dec16(x16[(size_t)n * K_TOT + kbase + i], mode);
    }
  }
  const int g = t >> 3, zsh = (g & 7) * 4, zword = g >> 3;
  for (int it = 0; it < ITERS; ++it) {
    const int obase = blockIdx.x * (ITERS * O_PER_IT) + it * O_PER_IT;
    #pragma unroll
    for (int oi = 0; oi < O_PER_IT; ++oi) {
      const int o = obase + oi;
      const uint32_t zw = qzeros[o * 8 + zword];
      const float z = (float)((zw >> zsh) & 15u);
      const float s = (mode == 2) ? scF[o * 64 + g] : dec16(sc16[o * 64 + g], mode);
      const uint32_t w0 = qweight[(size_t)o * KW + 2 * t];
      const uint32_t w1 = qweight[(size_t)o * KW + 2 * t + 1];
      float d[M_ROWS];
      #pragma unroll
      for (int n = 0; n < M_ROWS; ++n) d[n] = 0.f;
      const uint32_t wv[2] = { w0, w1 };
      #pragma unroll
      for (int w = 0; w < 2; ++w)
        #pragma unroll
        for (int j = 0; j < 8; ++j) {
          const float q = (float)((wv[w] >> (4 * j)) & 15u);
          const float wgt = s * (q - z);
          #pragma unroll
          for (int n = 0; n < M_ROWS; ++n) d[n] = fmaf(wgt, xf[n][8 * w + j], d[n]);
        }
      #pragma unroll
      for (int n = 0; n < M_ROWS; ++n) lds[oi][n][t] = d[n];
    }
    __syncthreads();
    {
      const int wvid = t >> 6, lanei = t & 63;
      #pragma unroll
      for (int cc2 = 0; cc2 < 2; ++cc2) {
        const int p = 2 * wvid + cc2, oi = p >> 3, n = p & 7;
        float v = 0.f;
        #pragma unroll
        for (int i = 0; i < 8; ++i) v += lds[oi][n][lanei + 64 * i];
        v += __shfl_xor(v, 32); v += __shfl_xor(v, 16); v += __shfl_xor(v, 8);
        v += __shfl_xor(v, 4);  v += __shfl_xor(v, 2);  v += __shfl_xor(v, 1);
        if (lanei == 0) {
          const int o = obase + oi;
          const float b = (mode == 2) ? bF[o] : dec16(b16[o], mode);
          const float r = v + b;
          const size_t idx = (size_t)n * O_TOT + o;
          if (mode == 0)      ((__hip_bfloat16*)outv)[idx] = __float2bfloat16(r);
          else if (mode == 1) { union { uint16_t u; _Float16 h; } cc; cc.h = (_Float16)r;
                                ((uint16_t*)outv)[idx] = cc.u; }
          else                ((float*)outv)[idx] = r;
        }
      }
    }
    __syncthreads();
  }
}

extern "C" void kernel_launch(void* const* d_in, const int* in_sizes, int n_in,
                              void* d_out, int out_size, void* d_ws, size_t ws_size,
                              hipStream_t stream)
{
  const uint16_t* x       = (const uint16_t*)d_in[0];
  const uint32_t* qweight = (const uint32_t*)d_in[1];
  const uint32_t* qzeros  = (const uint32_t*)d_in[2];
  const uint16_t* scales  = (const uint16_t*)d_in[3];
  const uint16_t* bias    = (const uint16_t*)d_in[4];
  int* flag = (int*)d_ws;
  uint8_t* ws = (uint8_t*)d_ws;

  hipLaunchKernelGGL(sniff_kernel, dim3(1), dim3(64), 0, stream, x, flag);

  if (ws_size >= WS_NEED_V9) {
    float* part = (float*)(ws + WS_PART);
    hipLaunchKernelGGL(prep_kernel, dim3(32), dim3(256), 0, stream, x, ws, flag);
    hipLaunchKernelGGL(sct_kernel,  dim3(448), dim3(256), 0, stream, scales, ws, flag);
    hipLaunchKernelGGL(wq_mfma3_kernel, dim3(3584), dim3(256), 0, stream,
                       qweight, qzeros, ws, part);
    hipLaunchKernelGGL(reduce_kernel, dim3(224), dim3(256), 0, stream,
                       part, bias, d_out, flag);
  } else if (ws_size >= WS_NEED_R7) {
    hipLaunchKernelGGL(prep_kernel, dim3(32), dim3(256), 0, stream, x, ws, flag);
    hipLaunchKernelGGL(wq_mfma_kernel, dim3(1792), dim3(256), 0, stream,
                       qweight, qzeros, scales, bias, d_out, ws, flag);
  } else {
    hipLaunchKernelGGL(wq_fallback_kernel, dim3(NBLK), dim3(NTHR), 0, stream,
                       x, qweight, qzeros, scales, bias, d_out, flag);
  }
}